// Round 6
// baseline (258.396 us; speedup 1.0000x reference)
//
#include <hip/hip_runtime.h>
#include <hip/hip_fp16.h>
#include <math.h>

#define NDIM 1024
#define KDIM 64
#define BDIM 256
#define BKDIM 16384

typedef unsigned short u16;
typedef __attribute__((ext_vector_type(8))) short bf16x8;
typedef __attribute__((ext_vector_type(4))) float f32x4;

__device__ __forceinline__ float bf2f(u16 u) {
  union { unsigned u; float f; } x; x.u = ((unsigned)u) << 16; return x.f;
}
__device__ __forceinline__ u16 f2bf(float f) {
  union { float f; unsigned u; } x; x.f = f;
  unsigned u = x.u;
  u += 0x7fffu + ((u >> 16) & 1u);   // RNE
  return (u16)(u >> 16);
}

// async 16B global->LDS (DMA, no VGPR roundtrip). LDS side must be
// wave-uniform base + lane*16; global side is per-lane (free gather).
__device__ __forceinline__ void async16(const u16* g, u16* s) {
  __builtin_amdgcn_global_load_lds(
      (const __attribute__((address_space(1))) unsigned int*)g,
      (__attribute__((address_space(3))) unsigned int*)s,
      16, 0, 0);
}

// ------ K_PRE: blocks [0,1024) = row logsumexp of A_logits/T;
//               blocks [1024,2048) = W sinkhorn (verbatim bodies, merged to
//               cut a launch gap; both depend on nothing). --------------------
__global__ __launch_bounds__(256) void k_pre(const float* __restrict__ Alog,
                                             float* __restrict__ r,
                                             const float* __restrict__ W1,
                                             const float* __restrict__ WV,
                                             u16* __restrict__ Wt) {
  __shared__ float sred[256];
  __shared__ float sla[64 * 65];
  int t = threadIdx.x;
  if (blockIdx.x < 1024) {
    // ---- row logsumexp ----
    int m = blockIdx.x;
    float v[4], mx = -3.0e38f;
#pragma unroll
    for (int j = 0; j < 4; j++) {
      v[j] = Alog[m * NDIM + t + j * 256] * 5.0f;
      mx = fmaxf(mx, v[j]);
    }
    sred[t] = mx; __syncthreads();
    for (int s = 128; s > 0; s >>= 1) { if (t < s) sred[t] = fmaxf(sred[t], sred[t + s]); __syncthreads(); }
    float bm = sred[0]; __syncthreads();
    float sm = 0.f;
#pragma unroll
    for (int j = 0; j < 4; j++) sm += __expf(v[j] - bm);
    sred[t] = sm; __syncthreads();
    for (int s = 128; s > 0; s >>= 1) { if (t < s) sred[t] += sred[t + s]; __syncthreads(); }
    if (t == 0) r[m] = bm + __logf(sred[0]);
  } else {
    // ---- W_logits = W1@WV, per-block sinkhorn, Wt[t][o][i] bf16 ----
    int tb = blockIdx.x - 1024;
    int d = t >> 2, q = t & 3;      // row d, col segment q*16..q*16+15
    float w1[8];
#pragma unroll
    for (int k = 0; k < 8; k++) w1[k] = W1[tb * 8 + k];
    float la[16];
#pragma unroll
    for (int j = 0; j < 16; j++) la[j] = 0.f;
#pragma unroll
    for (int k = 0; k < 8; k++) {
      float wk = w1[k];
      const float4* base = (const float4*)&WV[k * 4096 + d * 64 + q * 16];
#pragma unroll
      for (int v = 0; v < 4; v++) {
        float4 f = base[v];
        la[v * 4 + 0] += wk * f.x; la[v * 4 + 1] += wk * f.y;
        la[v * 4 + 2] += wk * f.z; la[v * 4 + 3] += wk * f.w;
      }
    }
    float mx = -3.0e38f;
#pragma unroll
    for (int j = 0; j < 16; j++) { la[j] *= 5.0f; mx = fmaxf(mx, la[j]); }
    float sm = 0.f;
#pragma unroll
    for (int j = 0; j < 16; j++) sm += __expf(la[j] - mx);
    for (int off = 1; off < 4; off <<= 1) {   // combine 4 lanes of a row
      float mo = __shfl_xor(mx, off), so = __shfl_xor(sm, off);
      float mn = fmaxf(mx, mo);
      sm = sm * __expf(mx - mn) + so * __expf(mo - mn);
      mx = mn;
    }
    float rl = mx + __logf(sm);
#pragma unroll
    for (int j = 0; j < 16; j++) sla[d * 65 + q * 16 + j] = la[j] - rl;
    __syncthreads();
    int e = t >> 2, jj = t & 3;     // col e, row segment jj*16..jj*16+15
    float lb[16]; float m2 = -3.0e38f;
#pragma unroll
    for (int i = 0; i < 16; i++) { lb[i] = sla[(jj * 16 + i) * 65 + e]; m2 = fmaxf(m2, lb[i]); }
    float s2 = 0.f;
#pragma unroll
    for (int i = 0; i < 16; i++) s2 += __expf(lb[i] - m2);
    for (int off = 1; off < 4; off <<= 1) {
      float mo = __shfl_xor(m2, off), so = __shfl_xor(s2, off);
      float mn = fmaxf(m2, mo);
      s2 = s2 * __expf(m2 - mn) + so * __expf(mo - mn);
      m2 = mn;
    }
    float cl = m2 + __logf(s2);
#pragma unroll
    for (int i = 0; i < 16; i++)
      Wt[tb * 4096 + e * 64 + jj * 16 + i] = f2bf(__expf(lb[i] - cl));  // Wt[t][o][i]=W[i][o]
  }
}

// ------ K4: x_local = x@W per n, output ROW-MAJOR xln[bk][m] bf16.
// n8 swizzled so the 8 blocks writing the 8 chunks of any 128B line share an
// XCD -> chunks merge in that XCD's L2. (256,2) is gemm1's natural occupancy
// (acc[8][4] = 128 acc regs); kept SEPARATE from col_dt2 (round-5 lesson:
// merging put the latency-bound strided pass under this 2-blk/CU cap, +20us).
__global__ __launch_bounds__(256, 2) void k_gemm1c(const float* __restrict__ x,
                                                   const u16* __restrict__ Wt,
                                                   u16* __restrict__ xln) {
  int bx = blockIdx.x, bt = blockIdx.y, t = threadIdx.x;
  int n8 = (bx & 15) * 8 + (bx >> 4);   // bijective; line-group g = bx&15
  int w = t >> 6, l = t & 63, q = l >> 4, lr = l & 15;
  int n0 = n8 * 8;
  const float* xb = x + (size_t)(bt * 64 + w * 16 + lr) * 65536 + n0 * 64;
  f32x4 acc[8][4] = {};
#pragma unroll
  for (int n = 0; n < 8; n++) {
#pragma unroll
    for (int ks = 0; ks < 2; ks++) {
      const float* xr = xb + n * 64 + ks * 32 + q * 8;
      float4 v0 = *(const float4*)xr;
      float4 v1 = *(const float4*)(xr + 4);
      float vf[8] = {v0.x, v0.y, v0.z, v0.w, v1.x, v1.y, v1.z, v1.w};
      bf16x8 ah, al;
#pragma unroll
      for (int j = 0; j < 8; j++) {
        u16 h = f2bf(vf[j]);
        ah[j] = (short)h;
        al[j] = (short)f2bf(vf[j] - bf2f(h));
      }
#pragma unroll
      for (int ni = 0; ni < 4; ni++) {
        bf16x8 bfr = *(const bf16x8*)&Wt[(size_t)(n0 + n) * 4096 + (ni * 16 + lr) * 64 + ks * 32 + q * 8];
        acc[n][ni] = __builtin_amdgcn_mfma_f32_16x16x32_bf16(ah, bfr, acc[n][ni], 0, 0, 0);
        acc[n][ni] = __builtin_amdgcn_mfma_f32_16x16x32_bf16(al, bfr, acc[n][ni], 0, 0, 0);
      }
    }
  }
#pragma unroll
  for (int ni = 0; ni < 4; ni++) {
#pragma unroll
    for (int reg = 0; reg < 4; reg++) {
      int bk = (bt * 64 + w * 16 + q * 4 + reg) * 64 + ni * 16 + lr;
      bf16x8 o;
#pragma unroll
      for (int n = 0; n < 8; n++) o[n] = (short)f2bf(acc[n][ni][reg]);
      *(bf16x8*)&xln[(size_t)bk * 1024 + n0] = o;   // 16B chunk of row bk
    }
  }
}

// ------ K2: col logsumexp; Dt'[n][m] = gamma[m]*(A[m][n] - 1/N) bf16;
//            gA/bA. Separate kernel at default occupancy (latency-bound). ----
__global__ __launch_bounds__(256) void k_col_dt2(const float* __restrict__ Alog,
                                                 const float* __restrict__ r,
                                                 const float* __restrict__ g2,
                                                 const float* __restrict__ b2,
                                                 u16* __restrict__ Dt,
                                                 float* __restrict__ gAc,
                                                 float* __restrict__ bAc) {
  int n = blockIdx.x, t = threadIdx.x;
  float v[4], mx = -3.0e38f;
#pragma unroll
  for (int j = 0; j < 4; j++) {
    int m = t + j * 256;
    v[j] = Alog[m * NDIM + n] * 5.0f - r[m];
    mx = fmaxf(mx, v[j]);
  }
  __shared__ float sred[256];
  sred[t] = mx; __syncthreads();
  for (int s = 128; s > 0; s >>= 1) { if (t < s) sred[t] = fmaxf(sred[t], sred[t + s]); __syncthreads(); }
  float bm = sred[0]; __syncthreads();
  float sm = 0.f;
#pragma unroll
  for (int j = 0; j < 4; j++) sm += __expf(v[j] - bm);
  sred[t] = sm; __syncthreads();
  for (int s = 128; s > 0; s >>= 1) { if (t < s) sred[t] += sred[t + s]; __syncthreads(); }
  float cn = bm + __logf(sred[0]);
  float ga = 0.f, ba = 0.f;
#pragma unroll
  for (int j = 0; j < 4; j++) {
    int m = t + j * 256;
    float e = __expf(v[j] - cn);
    float gm = g2[m];
    Dt[n * NDIM + m] = f2bf(gm * (e - 0.0009765625f));
    ga += gm * e; ba += b2[m] * e;
  }
  __syncthreads();
  sred[t] = ga; __syncthreads();
  for (int s = 128; s > 0; s >>= 1) { if (t < s) sred[t] += sred[t + s]; __syncthreads(); }
  if (t == 0) gAc[n] = sred[0];
  __syncthreads();
  sred[t] = ba; __syncthreads();
  for (int s = 128; s > 0; s >>= 1) { if (t < s) sred[t] += sred[t + s]; __syncthreads(); }
  if (t == 0) bAc[n] = sred[0];
}

// ------ K5 v3: fused LN stats per bk row (row-major xln), direct e1/e2/e3.
// 16 lanes per row, 256B-contiguous group reads, shfl_xor reduce. No partials.
__global__ __launch_bounds__(256) void k_stat3(const u16* __restrict__ xln,
                                               const float* __restrict__ g2,
                                               float* __restrict__ e1,
                                               float* __restrict__ e2,
                                               float* __restrict__ e3) {
  int t = threadIdx.x;
  int row = blockIdx.x * 16 + (t >> 4);
  int c = t & 15;
  const u16* xr = xln + (size_t)row * 1024 + c * 8;
  float S = 0.f, Q = 0.f, W = 0.f;
#pragma unroll
  for (int j = 0; j < 8; j++) {
    bf16x8 v = *(const bf16x8*)&xr[j * 128];
    const float* gp = g2 + j * 128 + c * 8;
    float4 g0 = *(const float4*)gp;
    float4 g1 = *(const float4*)(gp + 4);
    float gg[8] = {g0.x, g0.y, g0.z, g0.w, g1.x, g1.y, g1.z, g1.w};
#pragma unroll
    for (int k = 0; k < 8; k++) {
      float f = bf2f((u16)v[k]);
      S += f; Q += f * f; W += f * gg[k];
    }
  }
#pragma unroll
  for (int off = 1; off < 16; off <<= 1) {
    S += __shfl_xor(S, off);
    Q += __shfl_xor(Q, off);
    W += __shfl_xor(W, off);
  }
  if (c == 0) {
    float m_ = S * (1.0f / 1024.0f);
    float var = Q * (1.0f / 1024.0f) - m_ * m_;
    float a = rsqrtf(var + 1e-5f);
    e1[row] = a;
    e2[row] = a * W * (1.0f / 1024.0f);
    e3[row] = -a * m_;
  }
}

// ------ K6 v6: proven 2-barrier staging + MFMA loop; LN-folded epilogue via
// LDS-staged operands (dead lA reused). Register-pressure ladder (measured):
//   plain+reg-epilogue: 140 VGPR, 3 blk/CU -> 102us (panel refetch)
//   LDS-epilogue+cap102: acc spilled -> 112us (+114MB writes)
//   LDS-epilogue+cap128: partial spill -> 70us (+56MB writes)
// => LDS epilogue with NO cap: compiler's natural ~100-110 unified regs,
//    no spill, 4-5 blk/CU — the baseline 52us regime.
__global__ __launch_bounds__(256) void k_gemm2f(const u16* __restrict__ Dt,
                                                const u16* __restrict__ xln,
                                                const float* __restrict__ e1,
                                                const float* __restrict__ e2,
                                                const float* __restrict__ e3,
                                                const float* __restrict__ gAc,
                                                const float* __restrict__ bAc,
                                                float* __restrict__ out) {
  __shared__ __align__(16) u16 lA[128 * 64];  // [n2_local][m], swizzled
  __shared__ __align__(16) u16 lB[128 * 64];  // [bk_local][m], swizzled
  int bkt = blockIdx.x, n2t = blockIdx.y;
  int t = threadIdx.x, w = t >> 6, l = t & 63;
  int q = l >> 4, lr = l & 15;
  int rr = l >> 3;                 // row within 8-row group (0..7)
  int cc = (l & 7) ^ rr;           // logical chunk this lane fetches
  const u16* gAp = Dt  + (size_t)(n2t * 128) * NDIM + cc * 8;
  const u16* gBp = xln + (size_t)(bkt * 128) * NDIM + cc * 8;
  f32x4 acc[4][4] = {};
  for (int kt = 0; kt < 16; kt++) {
#pragma unroll
    for (int j = 0; j < 4; j++) {
      int ci = j * 4 + w;
      int row = ci * 8 + rr;
      async16(gAp + (size_t)row * NDIM + kt * 64, &lA[ci * 512 + l * 8]);
      async16(gBp + (size_t)row * NDIM + kt * 64, &lB[ci * 512 + l * 8]);
    }
    __syncthreads();   // drains vmcnt (global_load_lds) per barrier semantics
#pragma unroll
    for (int ks = 0; ks < 2; ks++) {
      int pc = ((ks * 4 + q) ^ (lr & 7)) * 8;   // physical chunk offset (halves)
      bf16x8 af[4], bfr[4];
#pragma unroll
      for (int mi = 0; mi < 4; mi++)
        af[mi] = *(const bf16x8*)&lA[((w >> 1) * 64 + mi * 16 + lr) * 64 + pc];
#pragma unroll
      for (int ni = 0; ni < 4; ni++)
        bfr[ni] = *(const bf16x8*)&lB[((w & 1) * 64 + ni * 16 + lr) * 64 + pc];
#pragma unroll
      for (int mi = 0; mi < 4; mi++)
#pragma unroll
        for (int ni = 0; ni < 4; ni++)
          acc[mi][ni] = __builtin_amdgcn_mfma_f32_16x16x32_bf16(af[mi], bfr[ni], acc[mi][ni], 0, 0, 0);
    }
    __syncthreads();   // tile consumed before next iter's DMA overwrites
  }
  // Stage epilogue operands into dead lA (2.5KB): [0)e1 [128)e2 [256)e3 [384)gA [512)bA
  float* sE = (float*)lA;
  if (t < 128) {
    sE[t]       = e1[bkt * 128 + t];
    sE[128 + t] = e2[bkt * 128 + t];
    sE[256 + t] = e3[bkt * 128 + t];
    sE[384 + t] = gAc[n2t * 128 + t];
    sE[512 + t] = bAc[n2t * 128 + t];
  }
  __syncthreads();
#pragma unroll
  for (int ni = 0; ni < 4; ni++) {
    int bkl = (w & 1) * 64 + ni * 16 + lr;       // local bk 0..127
    float a1 = sE[bkl], a2 = sE[128 + bkl], a3 = sE[256 + bkl];
    int bk = bkt * 128 + bkl;
    int b = bk >> 6, o = bk & 63;
#pragma unroll
    for (int mi = 0; mi < 4; mi++)
#pragma unroll
      for (int reg = 0; reg < 4; reg++) {
        int n2l = (w >> 1) * 64 + mi * 16 + q * 4 + reg;   // local n2 0..127
        int n2 = n2t * 128 + n2l;
        out[(size_t)b * 65536 + n2 * 64 + o] =
            a1 * acc[mi][ni][reg] + a2 + a3 * sE[384 + n2l] + sE[512 + n2l];
      }
  }
}

extern "C" void kernel_launch(void* const* d_in, const int* in_sizes, int n_in,
                              void* d_out, int out_size, void* d_ws, size_t ws_size,
                              hipStream_t stream) {
  const float* x    = (const float*)d_in[0];
  const float* Alog = (const float*)d_in[1];
  const float* W1   = (const float*)d_in[2];
  const float* WV   = (const float*)d_in[3];
  const float* g2   = (const float*)d_in[4];
  const float* b2   = (const float*)d_in[5];
  float* out = (float*)d_out;                       // fp32 output, 64 MiB
  char* ws = (char*)d_ws;

  u16*   xln = (u16*)(ws);                          // 32 MiB: [16384][1024] bf16
  u16*   Wt  = (u16*)(ws + 33554432ull);            //  8 MiB: [1024][4096] bf16 (dead after k_gemm1c)
  float* e1  = (float*)(ws + 33554432ull);          // 64 KiB, overlays Wt (written k_stat3 > last Wt read)
  float* e2  = (float*)(ws + 33619968ull);          // 64 KiB
  float* e3  = (float*)(ws + 33685504ull);          // 64 KiB
  u16*   Dt  = (u16*)(ws + 41943040ull);            //  2 MiB: [1024][1024] bf16 (gamma-folded)
  float* r   = (float*)(ws + 44040192ull);          //  4 KiB
  float* gAc = (float*)(ws + 44044288ull);          //  4 KiB
  float* bAc = (float*)(ws + 44048384ull);          //  4 KiB

  k_pre<<<dim3(2048), dim3(256), 0, stream>>>(Alog, r, W1, WV, Wt);
  k_gemm1c<<<dim3(128, 4), dim3(256), 0, stream>>>(x, Wt, xln);
  k_col_dt2<<<dim3(1024), dim3(256), 0, stream>>>(Alog, r, g2, b2, Dt, gAc, bAc);
  k_stat3<<<dim3(1024), dim3(256), 0, stream>>>(xln, g2, e1, e2, e3);
  k_gemm2f<<<dim3(128, 8), dim3(256), 0, stream>>>(Dt, xln, e1, e2, e3, gAc, bAc, out);
}

// Round 7
// 224.548 us; speedup vs baseline: 1.1507x; 1.1507x over previous
//
#include <hip/hip_runtime.h>
#include <hip/hip_fp16.h>
#include <math.h>

#define NDIM 1024
#define KDIM 64
#define BDIM 256
#define BKDIM 16384

typedef unsigned short u16;
typedef __attribute__((ext_vector_type(8))) short bf16x8;
typedef __attribute__((ext_vector_type(4))) float f32x4;

__device__ __forceinline__ float bf2f(u16 u) {
  union { unsigned u; float f; } x; x.u = ((unsigned)u) << 16; return x.f;
}
__device__ __forceinline__ u16 f2bf(float f) {
  union { float f; unsigned u; } x; x.f = f;
  unsigned u = x.u;
  u += 0x7fffu + ((u >> 16) & 1u);   // RNE
  return (u16)(u >> 16);
}

// async 16B global->LDS (DMA, no VGPR roundtrip). LDS side must be
// wave-uniform base + lane*16; global side is per-lane (free gather).
__device__ __forceinline__ void async16(const u16* g, u16* s) {
  __builtin_amdgcn_global_load_lds(
      (const __attribute__((address_space(1))) unsigned int*)g,
      (__attribute__((address_space(3))) unsigned int*)s,
      16, 0, 0);
}

// ------ K_PRE: blocks [0,1024) = row logsumexp of A_logits/T;
//               blocks [1024,2048) = W sinkhorn (verbatim bodies, merged to
//               cut a launch gap; both depend on nothing). --------------------
__global__ __launch_bounds__(256) void k_pre(const float* __restrict__ Alog,
                                             float* __restrict__ r,
                                             const float* __restrict__ W1,
                                             const float* __restrict__ WV,
                                             u16* __restrict__ Wt) {
  __shared__ float sred[256];
  __shared__ float sla[64 * 65];
  int t = threadIdx.x;
  if (blockIdx.x < 1024) {
    // ---- row logsumexp ----
    int m = blockIdx.x;
    float v[4], mx = -3.0e38f;
#pragma unroll
    for (int j = 0; j < 4; j++) {
      v[j] = Alog[m * NDIM + t + j * 256] * 5.0f;
      mx = fmaxf(mx, v[j]);
    }
    sred[t] = mx; __syncthreads();
    for (int s = 128; s > 0; s >>= 1) { if (t < s) sred[t] = fmaxf(sred[t], sred[t + s]); __syncthreads(); }
    float bm = sred[0]; __syncthreads();
    float sm = 0.f;
#pragma unroll
    for (int j = 0; j < 4; j++) sm += __expf(v[j] - bm);
    sred[t] = sm; __syncthreads();
    for (int s = 128; s > 0; s >>= 1) { if (t < s) sred[t] += sred[t + s]; __syncthreads(); }
    if (t == 0) r[m] = bm + __logf(sred[0]);
  } else {
    // ---- W_logits = W1@WV, per-block sinkhorn, Wt[t][o][i] bf16 ----
    int tb = blockIdx.x - 1024;
    int d = t >> 2, q = t & 3;      // row d, col segment q*16..q*16+15
    float w1[8];
#pragma unroll
    for (int k = 0; k < 8; k++) w1[k] = W1[tb * 8 + k];
    float la[16];
#pragma unroll
    for (int j = 0; j < 16; j++) la[j] = 0.f;
#pragma unroll
    for (int k = 0; k < 8; k++) {
      float wk = w1[k];
      const float4* base = (const float4*)&WV[k * 4096 + d * 64 + q * 16];
#pragma unroll
      for (int v = 0; v < 4; v++) {
        float4 f = base[v];
        la[v * 4 + 0] += wk * f.x; la[v * 4 + 1] += wk * f.y;
        la[v * 4 + 2] += wk * f.z; la[v * 4 + 3] += wk * f.w;
      }
    }
    float mx = -3.0e38f;
#pragma unroll
    for (int j = 0; j < 16; j++) { la[j] *= 5.0f; mx = fmaxf(mx, la[j]); }
    float sm = 0.f;
#pragma unroll
    for (int j = 0; j < 16; j++) sm += __expf(la[j] - mx);
    for (int off = 1; off < 4; off <<= 1) {   // combine 4 lanes of a row
      float mo = __shfl_xor(mx, off), so = __shfl_xor(sm, off);
      float mn = fmaxf(mx, mo);
      sm = sm * __expf(mx - mn) + so * __expf(mo - mn);
      mx = mn;
    }
    float rl = mx + __logf(sm);
#pragma unroll
    for (int j = 0; j < 16; j++) sla[d * 65 + q * 16 + j] = la[j] - rl;
    __syncthreads();
    int e = t >> 2, jj = t & 3;     // col e, row segment jj*16..jj*16+15
    float lb[16]; float m2 = -3.0e38f;
#pragma unroll
    for (int i = 0; i < 16; i++) { lb[i] = sla[(jj * 16 + i) * 65 + e]; m2 = fmaxf(m2, lb[i]); }
    float s2 = 0.f;
#pragma unroll
    for (int i = 0; i < 16; i++) s2 += __expf(lb[i] - m2);
    for (int off = 1; off < 4; off <<= 1) {
      float mo = __shfl_xor(m2, off), so = __shfl_xor(s2, off);
      float mn = fmaxf(m2, mo);
      s2 = s2 * __expf(m2 - mn) + so * __expf(mo - mn);
      m2 = mn;
    }
    float cl = m2 + __logf(s2);
#pragma unroll
    for (int i = 0; i < 16; i++)
      Wt[tb * 4096 + e * 64 + jj * 16 + i] = f2bf(__expf(lb[i] - cl));  // Wt[t][o][i]=W[i][o]
  }
}

// ------ K4: x_local = x@W per n, output ROW-MAJOR xln[bk][m] bf16.
// n8 swizzled so the 8 blocks writing the 8 chunks of any 128B line share an
// XCD -> chunks merge in that XCD's L2. (256,2) is gemm1's natural occupancy
// (acc[8][4] = 128 acc regs); kept SEPARATE from col_dt2 (round-5 lesson:
// merging put the latency-bound strided pass under this 2-blk/CU cap, +20us).
__global__ __launch_bounds__(256, 2) void k_gemm1c(const float* __restrict__ x,
                                                   const u16* __restrict__ Wt,
                                                   u16* __restrict__ xln) {
  int bx = blockIdx.x, bt = blockIdx.y, t = threadIdx.x;
  int n8 = (bx & 15) * 8 + (bx >> 4);   // bijective; line-group g = bx&15
  int w = t >> 6, l = t & 63, q = l >> 4, lr = l & 15;
  int n0 = n8 * 8;
  const float* xb = x + (size_t)(bt * 64 + w * 16 + lr) * 65536 + n0 * 64;
  f32x4 acc[8][4] = {};
#pragma unroll
  for (int n = 0; n < 8; n++) {
#pragma unroll
    for (int ks = 0; ks < 2; ks++) {
      const float* xr = xb + n * 64 + ks * 32 + q * 8;
      float4 v0 = *(const float4*)xr;
      float4 v1 = *(const float4*)(xr + 4);
      float vf[8] = {v0.x, v0.y, v0.z, v0.w, v1.x, v1.y, v1.z, v1.w};
      bf16x8 ah, al;
#pragma unroll
      for (int j = 0; j < 8; j++) {
        u16 h = f2bf(vf[j]);
        ah[j] = (short)h;
        al[j] = (short)f2bf(vf[j] - bf2f(h));
      }
#pragma unroll
      for (int ni = 0; ni < 4; ni++) {
        bf16x8 bfr = *(const bf16x8*)&Wt[(size_t)(n0 + n) * 4096 + (ni * 16 + lr) * 64 + ks * 32 + q * 8];
        acc[n][ni] = __builtin_amdgcn_mfma_f32_16x16x32_bf16(ah, bfr, acc[n][ni], 0, 0, 0);
        acc[n][ni] = __builtin_amdgcn_mfma_f32_16x16x32_bf16(al, bfr, acc[n][ni], 0, 0, 0);
      }
    }
  }
#pragma unroll
  for (int ni = 0; ni < 4; ni++) {
#pragma unroll
    for (int reg = 0; reg < 4; reg++) {
      int bk = (bt * 64 + w * 16 + q * 4 + reg) * 64 + ni * 16 + lr;
      bf16x8 o;
#pragma unroll
      for (int n = 0; n < 8; n++) o[n] = (short)f2bf(acc[n][ni][reg]);
      *(bf16x8*)&xln[(size_t)bk * 1024 + n0] = o;   // 16B chunk of row bk
    }
  }
}

// ------ K2: col logsumexp; Dt'[n][m] = gamma[m]*(A[m][n] - 1/N) bf16;
//            gA/bA. Separate kernel at default occupancy (latency-bound). ----
__global__ __launch_bounds__(256) void k_col_dt2(const float* __restrict__ Alog,
                                                 const float* __restrict__ r,
                                                 const float* __restrict__ g2,
                                                 const float* __restrict__ b2,
                                                 u16* __restrict__ Dt,
                                                 float* __restrict__ gAc,
                                                 float* __restrict__ bAc) {
  int n = blockIdx.x, t = threadIdx.x;
  float v[4], mx = -3.0e38f;
#pragma unroll
  for (int j = 0; j < 4; j++) {
    int m = t + j * 256;
    v[j] = Alog[m * NDIM + n] * 5.0f - r[m];
    mx = fmaxf(mx, v[j]);
  }
  __shared__ float sred[256];
  sred[t] = mx; __syncthreads();
  for (int s = 128; s > 0; s >>= 1) { if (t < s) sred[t] = fmaxf(sred[t], sred[t + s]); __syncthreads(); }
  float bm = sred[0]; __syncthreads();
  float sm = 0.f;
#pragma unroll
  for (int j = 0; j < 4; j++) sm += __expf(v[j] - bm);
  sred[t] = sm; __syncthreads();
  for (int s = 128; s > 0; s >>= 1) { if (t < s) sred[t] += sred[t + s]; __syncthreads(); }
  float cn = bm + __logf(sred[0]);
  float ga = 0.f, ba = 0.f;
#pragma unroll
  for (int j = 0; j < 4; j++) {
    int m = t + j * 256;
    float e = __expf(v[j] - cn);
    float gm = g2[m];
    Dt[n * NDIM + m] = f2bf(gm * (e - 0.0009765625f));
    ga += gm * e; ba += b2[m] * e;
  }
  __syncthreads();
  sred[t] = ga; __syncthreads();
  for (int s = 128; s > 0; s >>= 1) { if (t < s) sred[t] += sred[t + s]; __syncthreads(); }
  if (t == 0) gAc[n] = sred[0];
  __syncthreads();
  sred[t] = ba; __syncthreads();
  for (int s = 128; s > 0; s >>= 1) { if (t < s) sred[t] += sred[t + s]; __syncthreads(); }
  if (t == 0) bAc[n] = sred[0];
}

// ------ K5 v3: fused LN stats per bk row (row-major xln), direct e1/e2/e3.
// 16 lanes per row, 256B-contiguous group reads, shfl_xor reduce. No partials.
__global__ __launch_bounds__(256) void k_stat3(const u16* __restrict__ xln,
                                               const float* __restrict__ g2,
                                               float* __restrict__ e1,
                                               float* __restrict__ e2,
                                               float* __restrict__ e3) {
  int t = threadIdx.x;
  int row = blockIdx.x * 16 + (t >> 4);
  int c = t & 15;
  const u16* xr = xln + (size_t)row * 1024 + c * 8;
  float S = 0.f, Q = 0.f, W = 0.f;
#pragma unroll
  for (int j = 0; j < 8; j++) {
    bf16x8 v = *(const bf16x8*)&xr[j * 128];
    const float* gp = g2 + j * 128 + c * 8;
    float4 g0 = *(const float4*)gp;
    float4 g1 = *(const float4*)(gp + 4);
    float gg[8] = {g0.x, g0.y, g0.z, g0.w, g1.x, g1.y, g1.z, g1.w};
#pragma unroll
    for (int k = 0; k < 8; k++) {
      float f = bf2f((u16)v[k]);
      S += f; Q += f * f; W += f * gg[k];
    }
  }
#pragma unroll
  for (int off = 1; off < 16; off <<= 1) {
    S += __shfl_xor(S, off);
    Q += __shfl_xor(Q, off);
    W += __shfl_xor(W, off);
  }
  if (c == 0) {
    float m_ = S * (1.0f / 1024.0f);
    float var = Q * (1.0f / 1024.0f) - m_ * m_;
    float a = rsqrtf(var + 1e-5f);
    e1[row] = a;
    e2[row] = a * W * (1.0f / 1024.0f);
    e3[row] = -a * m_;
  }
}

// ------ K6 v7: proven 2-barrier staging + MFMA loop; LN-folded epilogue.
// Round-6 lesson: with the ni loop INSIDE the (mi,reg) consumers, the 32
// n2-dependent sE reads were loop-invariant -> LLVM hoisted them -> 136 VGPR
// -> 3 blk/CU -> panel refetch (+33MB) and 91us. This version flips the nest:
// (mi,reg) outer (2 fresh sE reads each), ni inner using 12 hoisted per-bk
// scalars; sched_barrier(0) per mi group pins the reads in place. Target:
// <=128 VGPR (4-5 blk/CU), no spill, the baseline 52us regime.
__global__ __launch_bounds__(256) void k_gemm2g(const u16* __restrict__ Dt,
                                                const u16* __restrict__ xln,
                                                const float* __restrict__ e1,
                                                const float* __restrict__ e2,
                                                const float* __restrict__ e3,
                                                const float* __restrict__ gAc,
                                                const float* __restrict__ bAc,
                                                float* __restrict__ out) {
  __shared__ __align__(16) u16 lA[128 * 64];  // [n2_local][m], swizzled
  __shared__ __align__(16) u16 lB[128 * 64];  // [bk_local][m], swizzled
  int bkt = blockIdx.x, n2t = blockIdx.y;
  int t = threadIdx.x, w = t >> 6, l = t & 63;
  int q = l >> 4, lr = l & 15;
  int rr = l >> 3;                 // row within 8-row group (0..7)
  int cc = (l & 7) ^ rr;           // logical chunk this lane fetches
  const u16* gAp = Dt  + (size_t)(n2t * 128) * NDIM + cc * 8;
  const u16* gBp = xln + (size_t)(bkt * 128) * NDIM + cc * 8;
  f32x4 acc[4][4] = {};
  for (int kt = 0; kt < 16; kt++) {
#pragma unroll
    for (int j = 0; j < 4; j++) {
      int ci = j * 4 + w;
      int row = ci * 8 + rr;
      async16(gAp + (size_t)row * NDIM + kt * 64, &lA[ci * 512 + l * 8]);
      async16(gBp + (size_t)row * NDIM + kt * 64, &lB[ci * 512 + l * 8]);
    }
    __syncthreads();   // drains vmcnt (global_load_lds) per barrier semantics
#pragma unroll
    for (int ks = 0; ks < 2; ks++) {
      int pc = ((ks * 4 + q) ^ (lr & 7)) * 8;   // physical chunk offset (halves)
      bf16x8 af[4], bfr[4];
#pragma unroll
      for (int mi = 0; mi < 4; mi++)
        af[mi] = *(const bf16x8*)&lA[((w >> 1) * 64 + mi * 16 + lr) * 64 + pc];
#pragma unroll
      for (int ni = 0; ni < 4; ni++)
        bfr[ni] = *(const bf16x8*)&lB[((w & 1) * 64 + ni * 16 + lr) * 64 + pc];
#pragma unroll
      for (int mi = 0; mi < 4; mi++)
#pragma unroll
        for (int ni = 0; ni < 4; ni++)
          acc[mi][ni] = __builtin_amdgcn_mfma_f32_16x16x32_bf16(af[mi], bfr[ni], acc[mi][ni], 0, 0, 0);
    }
    __syncthreads();   // tile consumed before next iter's DMA overwrites
  }
  // Stage epilogue operands into dead lA (2.5KB): [0)e1 [128)e2 [256)e3 [384)gA [512)bA
  float* sE = (float*)lA;
  if (t < 128) {
    sE[t]       = e1[bkt * 128 + t];
    sE[128 + t] = e2[bkt * 128 + t];
    sE[256 + t] = e3[bkt * 128 + t];
    sE[384 + t] = gAc[n2t * 128 + t];
    sE[512 + t] = bAc[n2t * 128 + t];
  }
  __syncthreads();
  // 12 per-bk scalars hoisted once (invariant across the outer n2 loop):
  float a1v[4], a2v[4], a3v[4];
#pragma unroll
  for (int ni = 0; ni < 4; ni++) {
    int bkl = (w & 1) * 64 + ni * 16 + lr;       // local bk 0..127
    a1v[ni] = sE[bkl]; a2v[ni] = sE[128 + bkl]; a3v[ni] = sE[256 + bkl];
  }
  int bkb = bkt * 128 + (w & 1) * 64 + lr;       // bk for ni=0
#pragma unroll
  for (int mi = 0; mi < 4; mi++) {
    __builtin_amdgcn_sched_barrier(0);           // pin sE reads per mi group
#pragma unroll
    for (int reg = 0; reg < 4; reg++) {
      int n2l = (w >> 1) * 64 + mi * 16 + q * 4 + reg;   // local n2 0..127
      float gg = sE[384 + n2l], bb = sE[512 + n2l];
      int n2 = n2t * 128 + n2l;
#pragma unroll
      for (int ni = 0; ni < 4; ni++) {
        int bk = bkb + ni * 16;
        int b = bk >> 6, o = bk & 63;
        out[(size_t)b * 65536 + n2 * 64 + o] =
            a1v[ni] * acc[mi][ni][reg] + a2v[ni] + a3v[ni] * gg + bb;
      }
    }
  }
}

extern "C" void kernel_launch(void* const* d_in, const int* in_sizes, int n_in,
                              void* d_out, int out_size, void* d_ws, size_t ws_size,
                              hipStream_t stream) {
  const float* x    = (const float*)d_in[0];
  const float* Alog = (const float*)d_in[1];
  const float* W1   = (const float*)d_in[2];
  const float* WV   = (const float*)d_in[3];
  const float* g2   = (const float*)d_in[4];
  const float* b2   = (const float*)d_in[5];
  float* out = (float*)d_out;                       // fp32 output, 64 MiB
  char* ws = (char*)d_ws;

  u16*   xln = (u16*)(ws);                          // 32 MiB: [16384][1024] bf16
  u16*   Wt  = (u16*)(ws + 33554432ull);            //  8 MiB: [1024][4096] bf16 (dead after k_gemm1c)
  float* e1  = (float*)(ws + 33554432ull);          // 64 KiB, overlays Wt (written k_stat3 > last Wt read)
  float* e2  = (float*)(ws + 33619968ull);          // 64 KiB
  float* e3  = (float*)(ws + 33685504ull);          // 64 KiB
  u16*   Dt  = (u16*)(ws + 41943040ull);            //  2 MiB: [1024][1024] bf16 (gamma-folded)
  float* r   = (float*)(ws + 44040192ull);          //  4 KiB
  float* gAc = (float*)(ws + 44044288ull);          //  4 KiB
  float* bAc = (float*)(ws + 44048384ull);          //  4 KiB

  k_pre<<<dim3(2048), dim3(256), 0, stream>>>(Alog, r, W1, WV, Wt);
  k_gemm1c<<<dim3(128, 4), dim3(256), 0, stream>>>(x, Wt, xln);
  k_col_dt2<<<dim3(1024), dim3(256), 0, stream>>>(Alog, r, g2, b2, Dt, gAc, bAc);
  k_stat3<<<dim3(1024), dim3(256), 0, stream>>>(xln, g2, e1, e2, e3);
  k_gemm2g<<<dim3(128, 8), dim3(256), 0, stream>>>(Dt, xln, e1, e2, e3, gAc, bAc, out);
}

// Round 8
// 224.164 us; speedup vs baseline: 1.1527x; 1.0017x over previous
//
#include <hip/hip_runtime.h>
#include <hip/hip_fp16.h>
#include <math.h>

#define NDIM 1024
#define KDIM 64
#define BDIM 256
#define BKDIM 16384

typedef unsigned short u16;
typedef __attribute__((ext_vector_type(8))) short bf16x8;
typedef __attribute__((ext_vector_type(4))) short bf16x4;
typedef __attribute__((ext_vector_type(4))) float f32x4;

__device__ __forceinline__ float bf2f(u16 u) {
  union { unsigned u; float f; } x; x.u = ((unsigned)u) << 16; return x.f;
}
__device__ __forceinline__ u16 f2bf(float f) {
  union { float f; unsigned u; } x; x.f = f;
  unsigned u = x.u;
  u += 0x7fffu + ((u >> 16) & 1u);   // RNE
  return (u16)(u >> 16);
}

// async 16B global->LDS (DMA, no VGPR roundtrip). LDS side must be
// wave-uniform base + lane*16; global side is per-lane (free gather).
__device__ __forceinline__ void async16(const u16* g, u16* s) {
  __builtin_amdgcn_global_load_lds(
      (const __attribute__((address_space(1))) unsigned int*)g,
      (__attribute__((address_space(3))) unsigned int*)s,
      16, 0, 0);
}

// ------ K_PRE: blocks [0,1024) = row logsumexp of A_logits/T;
//               blocks [1024,2048) = W sinkhorn (verbatim bodies, merged to
//               cut a launch gap; both depend on nothing). --------------------
__global__ __launch_bounds__(256) void k_pre(const float* __restrict__ Alog,
                                             float* __restrict__ r,
                                             const float* __restrict__ W1,
                                             const float* __restrict__ WV,
                                             u16* __restrict__ Wt) {
  __shared__ float sred[256];
  __shared__ float sla[64 * 65];
  int t = threadIdx.x;
  if (blockIdx.x < 1024) {
    // ---- row logsumexp ----
    int m = blockIdx.x;
    float v[4], mx = -3.0e38f;
#pragma unroll
    for (int j = 0; j < 4; j++) {
      v[j] = Alog[m * NDIM + t + j * 256] * 5.0f;
      mx = fmaxf(mx, v[j]);
    }
    sred[t] = mx; __syncthreads();
    for (int s = 128; s > 0; s >>= 1) { if (t < s) sred[t] = fmaxf(sred[t], sred[t + s]); __syncthreads(); }
    float bm = sred[0]; __syncthreads();
    float sm = 0.f;
#pragma unroll
    for (int j = 0; j < 4; j++) sm += __expf(v[j] - bm);
    sred[t] = sm; __syncthreads();
    for (int s = 128; s > 0; s >>= 1) { if (t < s) sred[t] += sred[t + s]; __syncthreads(); }
    if (t == 0) r[m] = bm + __logf(sred[0]);
  } else {
    // ---- W_logits = W1@WV, per-block sinkhorn, Wt[t][o][i] bf16 ----
    int tb = blockIdx.x - 1024;
    int d = t >> 2, q = t & 3;      // row d, col segment q*16..q*16+15
    float w1[8];
#pragma unroll
    for (int k = 0; k < 8; k++) w1[k] = W1[tb * 8 + k];
    float la[16];
#pragma unroll
    for (int j = 0; j < 16; j++) la[j] = 0.f;
#pragma unroll
    for (int k = 0; k < 8; k++) {
      float wk = w1[k];
      const float4* base = (const float4*)&WV[k * 4096 + d * 64 + q * 16];
#pragma unroll
      for (int v = 0; v < 4; v++) {
        float4 f = base[v];
        la[v * 4 + 0] += wk * f.x; la[v * 4 + 1] += wk * f.y;
        la[v * 4 + 2] += wk * f.z; la[v * 4 + 3] += wk * f.w;
      }
    }
    float mx = -3.0e38f;
#pragma unroll
    for (int j = 0; j < 16; j++) { la[j] *= 5.0f; mx = fmaxf(mx, la[j]); }
    float sm = 0.f;
#pragma unroll
    for (int j = 0; j < 16; j++) sm += __expf(la[j] - mx);
    for (int off = 1; off < 4; off <<= 1) {   // combine 4 lanes of a row
      float mo = __shfl_xor(mx, off), so = __shfl_xor(sm, off);
      float mn = fmaxf(mx, mo);
      sm = sm * __expf(mx - mn) + so * __expf(mo - mn);
      mx = mn;
    }
    float rl = mx + __logf(sm);
#pragma unroll
    for (int j = 0; j < 16; j++) sla[d * 65 + q * 16 + j] = la[j] - rl;
    __syncthreads();
    int e = t >> 2, jj = t & 3;     // col e, row segment jj*16..jj*16+15
    float lb[16]; float m2 = -3.0e38f;
#pragma unroll
    for (int i = 0; i < 16; i++) { lb[i] = sla[(jj * 16 + i) * 65 + e]; m2 = fmaxf(m2, lb[i]); }
    float s2 = 0.f;
#pragma unroll
    for (int i = 0; i < 16; i++) s2 += __expf(lb[i] - m2);
    for (int off = 1; off < 4; off <<= 1) {
      float mo = __shfl_xor(m2, off), so = __shfl_xor(s2, off);
      float mn = fmaxf(m2, mo);
      s2 = s2 * __expf(m2 - mn) + so * __expf(mo - mn);
      m2 = mn;
    }
    float cl = m2 + __logf(s2);
#pragma unroll
    for (int i = 0; i < 16; i++)
      Wt[tb * 4096 + e * 64 + jj * 16 + i] = f2bf(__expf(lb[i] - cl));  // Wt[t][o][i]=W[i][o]
  }
}

// ------ K4 v5: x_local = x@W, row-major xln[bk][m] bf16. Round-7 change:
// 512 threads/block, each old wave's 8-n work split across two waves
// (h = w>>2 picks the n-half) -> acc[4][4] = 64 VGPR -> (512,4) = 16 waves/CU
// (2x the old (256,2) 8 waves) for this HBM-streaming kernel. Same grid, same
// global traffic & coalescing; two waves fill each 16B n8-chunk as 8B halves,
// so the 128B-line XCD-merge property (bx mod 8 grouping) is preserved.
__global__ __launch_bounds__(512, 4) void k_gemm1d(const float* __restrict__ x,
                                                   const u16* __restrict__ Wt,
                                                   u16* __restrict__ xln) {
  int bx = blockIdx.x, bt = blockIdx.y, t = threadIdx.x;
  int n8 = (bx & 15) * 8 + (bx >> 4);   // bijective; line-group g = bx&15
  int w = t >> 6, l = t & 63, q = l >> 4, lr = l & 15;
  int p = w & 3, h = w >> 2;            // b-subrange, n-half
  int nb = n8 * 8 + h * 4;
  const float* xb = x + (size_t)(bt * 64 + p * 16 + lr) * 65536;
  f32x4 acc[4][4] = {};
#pragma unroll
  for (int np = 0; np < 4; np++) {
    int n = nb + np;
#pragma unroll
    for (int ks = 0; ks < 2; ks++) {
      const float* xr = xb + n * 64 + ks * 32 + q * 8;
      float4 v0 = *(const float4*)xr;
      float4 v1 = *(const float4*)(xr + 4);
      float vf[8] = {v0.x, v0.y, v0.z, v0.w, v1.x, v1.y, v1.z, v1.w};
      bf16x8 ah, al;
#pragma unroll
      for (int j = 0; j < 8; j++) {
        u16 hh = f2bf(vf[j]);
        ah[j] = (short)hh;
        al[j] = (short)f2bf(vf[j] - bf2f(hh));
      }
#pragma unroll
      for (int ni = 0; ni < 4; ni++) {
        bf16x8 bfr = *(const bf16x8*)&Wt[(size_t)n * 4096 + (ni * 16 + lr) * 64 + ks * 32 + q * 8];
        acc[np][ni] = __builtin_amdgcn_mfma_f32_16x16x32_bf16(ah, bfr, acc[np][ni], 0, 0, 0);
        acc[np][ni] = __builtin_amdgcn_mfma_f32_16x16x32_bf16(al, bfr, acc[np][ni], 0, 0, 0);
      }
    }
  }
#pragma unroll
  for (int ni = 0; ni < 4; ni++) {
#pragma unroll
    for (int reg = 0; reg < 4; reg++) {
      int bk = (bt * 64 + p * 16 + q * 4 + reg) * 64 + ni * 16 + lr;
      bf16x4 o;
#pragma unroll
      for (int np = 0; np < 4; np++) o[np] = (short)f2bf(acc[np][ni][reg]);
      *(bf16x4*)&xln[(size_t)bk * 1024 + nb] = o;   // 8B half-chunk of row bk
    }
  }
}

// ------ K_POST: blocks [0,1024) = col logsumexp + Dt'/gA/bA (verbatim);
//                blocks [1024,2048) = LN stats e1/e2/e3 (verbatim stat3).
// Independent passes, both default-occupancy; merged to cut a launch gap and
// overlap col_dt2's latency-bound strided reads with stat3's streaming. -----
__global__ __launch_bounds__(256) void k_post(const float* __restrict__ Alog,
                                              const float* __restrict__ r,
                                              const float* __restrict__ g2,
                                              const float* __restrict__ b2,
                                              u16* __restrict__ Dt,
                                              float* __restrict__ gAc,
                                              float* __restrict__ bAc,
                                              const u16* __restrict__ xln,
                                              float* __restrict__ e1,
                                              float* __restrict__ e2,
                                              float* __restrict__ e3) {
  __shared__ float sred[256];
  int t = threadIdx.x;
  if (blockIdx.x < 1024) {
    // ---- col logsumexp; Dt'[n][m] = gamma[m]*(A[m][n]-1/N); gA; bA ----
    int n = blockIdx.x;
    float v[4], mx = -3.0e38f;
#pragma unroll
    for (int j = 0; j < 4; j++) {
      int m = t + j * 256;
      v[j] = Alog[m * NDIM + n] * 5.0f - r[m];
      mx = fmaxf(mx, v[j]);
    }
    sred[t] = mx; __syncthreads();
    for (int s = 128; s > 0; s >>= 1) { if (t < s) sred[t] = fmaxf(sred[t], sred[t + s]); __syncthreads(); }
    float bm = sred[0]; __syncthreads();
    float sm = 0.f;
#pragma unroll
    for (int j = 0; j < 4; j++) sm += __expf(v[j] - bm);
    sred[t] = sm; __syncthreads();
    for (int s = 128; s > 0; s >>= 1) { if (t < s) sred[t] += sred[t + s]; __syncthreads(); }
    float cn = bm + __logf(sred[0]);
    float ga = 0.f, ba = 0.f;
#pragma unroll
    for (int j = 0; j < 4; j++) {
      int m = t + j * 256;
      float e = __expf(v[j] - cn);
      float gm = g2[m];
      Dt[n * NDIM + m] = f2bf(gm * (e - 0.0009765625f));
      ga += gm * e; ba += b2[m] * e;
    }
    __syncthreads();
    sred[t] = ga; __syncthreads();
    for (int s = 128; s > 0; s >>= 1) { if (t < s) sred[t] += sred[t + s]; __syncthreads(); }
    if (t == 0) gAc[n] = sred[0];
    __syncthreads();
    sred[t] = ba; __syncthreads();
    for (int s = 128; s > 0; s >>= 1) { if (t < s) sred[t] += sred[t + s]; __syncthreads(); }
    if (t == 0) bAc[n] = sred[0];
  } else {
    // ---- LN stats per bk row -> e1/e2/e3 ----
    int row = (blockIdx.x - 1024) * 16 + (t >> 4);
    int c = t & 15;
    const u16* xr = xln + (size_t)row * 1024 + c * 8;
    float S = 0.f, Q = 0.f, W = 0.f;
#pragma unroll
    for (int j = 0; j < 8; j++) {
      bf16x8 v = *(const bf16x8*)&xr[j * 128];
      const float* gp = g2 + j * 128 + c * 8;
      float4 g0 = *(const float4*)gp;
      float4 g1 = *(const float4*)(gp + 4);
      float gg[8] = {g0.x, g0.y, g0.z, g0.w, g1.x, g1.y, g1.z, g1.w};
#pragma unroll
      for (int k = 0; k < 8; k++) {
        float f = bf2f((u16)v[k]);
        S += f; Q += f * f; W += f * gg[k];
      }
    }
#pragma unroll
    for (int off = 1; off < 16; off <<= 1) {
      S += __shfl_xor(S, off);
      Q += __shfl_xor(Q, off);
      W += __shfl_xor(W, off);
    }
    if (c == 0) {
      float m_ = S * (1.0f / 1024.0f);
      float var = Q * (1.0f / 1024.0f) - m_ * m_;
      float a = rsqrtf(var + 1e-5f);
      e1[row] = a;
      e2[row] = a * W * (1.0f / 1024.0f);
      e3[row] = -a * m_;
    }
  }
}

// ------ K6 v7 (UNCHANGED from round 7, the 61us/88-VGPR control):
// proven 2-barrier staging + MFMA loop; LN-folded epilogue with (mi,reg)
// outer / ni inner nest + sched_barrier(0) to keep sE reads un-hoisted.
__global__ __launch_bounds__(256) void k_gemm2g(const u16* __restrict__ Dt,
                                                const u16* __restrict__ xln,
                                                const float* __restrict__ e1,
                                                const float* __restrict__ e2,
                                                const float* __restrict__ e3,
                                                const float* __restrict__ gAc,
                                                const float* __restrict__ bAc,
                                                float* __restrict__ out) {
  __shared__ __align__(16) u16 lA[128 * 64];  // [n2_local][m], swizzled
  __shared__ __align__(16) u16 lB[128 * 64];  // [bk_local][m], swizzled
  int bkt = blockIdx.x, n2t = blockIdx.y;
  int t = threadIdx.x, w = t >> 6, l = t & 63;
  int q = l >> 4, lr = l & 15;
  int rr = l >> 3;                 // row within 8-row group (0..7)
  int cc = (l & 7) ^ rr;           // logical chunk this lane fetches
  const u16* gAp = Dt  + (size_t)(n2t * 128) * NDIM + cc * 8;
  const u16* gBp = xln + (size_t)(bkt * 128) * NDIM + cc * 8;
  f32x4 acc[4][4] = {};
  for (int kt = 0; kt < 16; kt++) {
#pragma unroll
    for (int j = 0; j < 4; j++) {
      int ci = j * 4 + w;
      int row = ci * 8 + rr;
      async16(gAp + (size_t)row * NDIM + kt * 64, &lA[ci * 512 + l * 8]);
      async16(gBp + (size_t)row * NDIM + kt * 64, &lB[ci * 512 + l * 8]);
    }
    __syncthreads();   // drains vmcnt (global_load_lds) per barrier semantics
#pragma unroll
    for (int ks = 0; ks < 2; ks++) {
      int pc = ((ks * 4 + q) ^ (lr & 7)) * 8;   // physical chunk offset (halves)
      bf16x8 af[4], bfr[4];
#pragma unroll
      for (int mi = 0; mi < 4; mi++)
        af[mi] = *(const bf16x8*)&lA[((w >> 1) * 64 + mi * 16 + lr) * 64 + pc];
#pragma unroll
      for (int ni = 0; ni < 4; ni++)
        bfr[ni] = *(const bf16x8*)&lB[((w & 1) * 64 + ni * 16 + lr) * 64 + pc];
#pragma unroll
      for (int mi = 0; mi < 4; mi++)
#pragma unroll
        for (int ni = 0; ni < 4; ni++)
          acc[mi][ni] = __builtin_amdgcn_mfma_f32_16x16x32_bf16(af[mi], bfr[ni], acc[mi][ni], 0, 0, 0);
    }
    __syncthreads();   // tile consumed before next iter's DMA overwrites
  }
  // Stage epilogue operands into dead lA (2.5KB): [0)e1 [128)e2 [256)e3 [384)gA [512)bA
  float* sE = (float*)lA;
  if (t < 128) {
    sE[t]       = e1[bkt * 128 + t];
    sE[128 + t] = e2[bkt * 128 + t];
    sE[256 + t] = e3[bkt * 128 + t];
    sE[384 + t] = gAc[n2t * 128 + t];
    sE[512 + t] = bAc[n2t * 128 + t];
  }
  __syncthreads();
  // 12 per-bk scalars hoisted once (invariant across the outer n2 loop):
  float a1v[4], a2v[4], a3v[4];
#pragma unroll
  for (int ni = 0; ni < 4; ni++) {
    int bkl = (w & 1) * 64 + ni * 16 + lr;       // local bk 0..127
    a1v[ni] = sE[bkl]; a2v[ni] = sE[128 + bkl]; a3v[ni] = sE[256 + bkl];
  }
  int bkb = bkt * 128 + (w & 1) * 64 + lr;       // bk for ni=0
#pragma unroll
  for (int mi = 0; mi < 4; mi++) {
    __builtin_amdgcn_sched_barrier(0);           // pin sE reads per mi group
#pragma unroll
    for (int reg = 0; reg < 4; reg++) {
      int n2l = (w >> 1) * 64 + mi * 16 + q * 4 + reg;   // local n2 0..127
      float gg = sE[384 + n2l], bb = sE[512 + n2l];
      int n2 = n2t * 128 + n2l;
#pragma unroll
      for (int ni = 0; ni < 4; ni++) {
        int bk = bkb + ni * 16;
        int b = bk >> 6, o = bk & 63;
        out[(size_t)b * 65536 + n2 * 64 + o] =
            a1v[ni] * acc[mi][ni][reg] + a2v[ni] + a3v[ni] * gg + bb;
      }
    }
  }
}

extern "C" void kernel_launch(void* const* d_in, const int* in_sizes, int n_in,
                              void* d_out, int out_size, void* d_ws, size_t ws_size,
                              hipStream_t stream) {
  const float* x    = (const float*)d_in[0];
  const float* Alog = (const float*)d_in[1];
  const float* W1   = (const float*)d_in[2];
  const float* WV   = (const float*)d_in[3];
  const float* g2   = (const float*)d_in[4];
  const float* b2   = (const float*)d_in[5];
  float* out = (float*)d_out;                       // fp32 output, 64 MiB
  char* ws = (char*)d_ws;

  u16*   xln = (u16*)(ws);                          // 32 MiB: [16384][1024] bf16
  u16*   Wt  = (u16*)(ws + 33554432ull);            //  8 MiB: [1024][4096] bf16 (dead after k_gemm1d)
  float* e1  = (float*)(ws + 33554432ull);          // 64 KiB, overlays Wt (written k_post > last Wt read)
  float* e2  = (float*)(ws + 33619968ull);          // 64 KiB
  float* e3  = (float*)(ws + 33685504ull);          // 64 KiB
  u16*   Dt  = (u16*)(ws + 41943040ull);            //  2 MiB: [1024][1024] bf16 (gamma-folded)
  float* r   = (float*)(ws + 44040192ull);          //  4 KiB
  float* gAc = (float*)(ws + 44044288ull);          //  4 KiB
  float* bAc = (float*)(ws + 44048384ull);          //  4 KiB

  k_pre<<<dim3(2048), dim3(256), 0, stream>>>(Alog, r, W1, WV, Wt);
  k_gemm1d<<<dim3(128, 4), dim3(512), 0, stream>>>(x, Wt, xln);
  k_post<<<dim3(2048), dim3(256), 0, stream>>>(Alog, r, g2, b2, Dt, gAc, bAc, xln, e1, e2, e3);
  k_gemm2g<<<dim3(128, 8), dim3(256), 0, stream>>>(Dt, xln, e1, e2, e3, gAc, bAc, out);
}